// Round 1
// baseline (7860.259 us; speedup 1.0000x reference)
//
#include <hip/hip_runtime.h>

typedef _Float16 half_t;
typedef _Float16 half2_t __attribute__((ext_vector_type(2)));
typedef unsigned int       u32;
typedef unsigned short     u16;

#define BB    32      // batch
#define TT    2048    // seq len
#define HH    256     // hidden = input dim
#define G3    768     // 3*H
#define DEPTH 8       // ring-buffer depth (power of 2)

// ws layout (bytes), ~1.65 MB total:
//   0       : flags[3][BB] padded 128B each (slot = u32[DEPTH] in first 32B)   (12288)
//   12288   : cons [3][BB] padded 128B each                                    (12288)
//   24576   : xg0q [BB][DEPTH][G3] f32   (786432)
//   811008  : xg1q [BB][DEPTH][G3] f32   (786432)
//   1597440 : h0q  [BB][DEPTH][HH] f16   (131072)
#define OFF_CONS 12288
#define OFF_XG0  24576
#define OFF_XG1  811008
#define OFF_H0   1597440
#define FLAGS_BYTES 24576

__device__ __forceinline__ half2_t f2h2(float a, float b) {
  half2_t r; r.x = (half_t)a; r.y = (half_t)b; return r;
}
__device__ __forceinline__ float sigm(float v) {
  return __builtin_amdgcn_rcpf(1.f + __builtin_amdgcn_exp2f(v * -1.4426950408889634f));
}
__device__ __forceinline__ float tanh_fast(float v) {
  return 1.f - 2.f * __builtin_amdgcn_rcpf(1.f + __builtin_amdgcn_exp2f(v * 2.8853900817779268f));
}
__device__ __forceinline__ void wait_ge(u32* p, u32 v) {
  while (__hip_atomic_load(p, __ATOMIC_ACQUIRE, __HIP_MEMORY_SCOPE_AGENT) < v)
    __builtin_amdgcn_s_sleep(1);
}
__device__ __forceinline__ float ld_f32_agent(const float* p) {
  return __hip_atomic_load(p, __ATOMIC_RELAXED, __HIP_MEMORY_SCOPE_AGENT);
}
__device__ __forceinline__ u32 ld_u32_agent(const u32* p) {
  return __hip_atomic_load(p, __ATOMIC_RELAXED, __HIP_MEMORY_SCOPE_AGENT);
}
__device__ __forceinline__ void st_f32_agent(float* p, float v) {
  __hip_atomic_store(p, v, __ATOMIC_RELAXED, __HIP_MEMORY_SCOPE_AGENT);
}
__device__ __forceinline__ void st_u16_agent(u16* p, u16 v) {
  __hip_atomic_store(p, v, __ATOMIC_RELAXED, __HIP_MEMORY_SCOPE_AGENT);
}

// 128 blocks: blockIdx = stage*32 + chain.
//   stage 0: xg0 = Wih0@x_t + bih0       stage 1: GRU cell layer 0 (Whh0)
//   stage 2: xg1 = Wih1@h0_t + bih1      stage 3: GRU cell layer 1 (Whh1) -> out (fp32)
// 512 threads: thread (i=tid>>1, c=tid&1) owns rows {i,256+i,512+i} x K-half c.
// Weights = 192 VGPRs/thread as f16 pairs. R6 showed the compiler REMATERIALIZES the
// weight loads inside the t-loop (VGPR_Count=64, 384KB/step L2 restream) — so after the
// init loads, every weight register is laundered through an empty asm() to erase its
// memory provenance: the RA must keep them live. waves_per_eu(2,2) grants a 256-VGPR
// budget (512 thr = 8 waves = 2/SIMD at 1 block/CU).
__global__ __launch_bounds__(512) __attribute__((amdgpu_waves_per_eu(2, 2)))
void gru_pipe(const float* __restrict__ x,     // fp32 [B][T][H]
              const float* __restrict__ Wih,   // fp32 [2][768][256]
              const float* __restrict__ Whh,   // fp32 [2][768][256]
              const float* __restrict__ bih,   // fp32 [2][768]
              const float* __restrict__ bhh,   // fp32 [2][768]
              float* __restrict__ out,         // fp32 [B][T][H]
              uint8_t* __restrict__ ws)
{
  const int stage = blockIdx.x >> 5;
  const int chain = blockIdx.x & 31;
  const int tid   = threadIdx.x;
  const int i     = tid >> 1;   // 0..255
  const int c     = tid & 1;    // k-half
  const int l     = stage >> 1; // layer
  const bool rec  = (stage & 1);

  u32*    flags = (u32*)ws;                  // [(link*32+chain)*32 + slot]
  u32*    cons  = (u32*)(ws + OFF_CONS);     // [(link*32+chain)*32]
  float*  xg0q  = (float*)(ws + OFF_XG0);
  float*  xg1q  = (float*)(ws + OFF_XG1);
  half_t* h0q   = (half_t*)(ws + OFF_H0);

  const float* Wm = (rec ? Whh : Wih) + (size_t)l * G3 * HH;
  const float* bv = (rec ? bhh : bih) + (size_t)l * G3;

  // ---- weights -> 192 VGPRs (fp32 -> f16 RNE), then launder via asm so the
  //      compiler cannot rematerialize the loads inside the t-loop ----
  u32   w[3][64];
  float bs[3];
#pragma unroll
  for (int r = 0; r < 3; ++r) {
    const int row = r * 256 + i;
    const float4* wp = (const float4*)(Wm + (size_t)row * HH + c * 128);
#pragma unroll
    for (int j = 0; j < 32; ++j) {
      float4 v = wp[j];
      w[r][2 * j]     = __builtin_bit_cast(u32, f2h2(v.x, v.y));
      w[r][2 * j + 1] = __builtin_bit_cast(u32, f2h2(v.z, v.w));
    }
    bs[r] = bv[row];
  }
#pragma unroll
  for (int r = 0; r < 3; ++r)
#pragma unroll
    for (int j = 0; j < 64; ++j)
      asm volatile("" : "+v"(w[r][j]));   // opaque: no memory provenance, must stay live

  __shared__ __align__(16) half2_t hb[2][128];   // ping-pong input vector (256 f16)
  if (tid < 128) {
    half2_t z; z.x = (half_t)0.f; z.y = (half_t)0.f;
    hb[0][tid] = z; hb[1][tid] = z;
  }

  float   hprev = 0.f;
  half2_t xreg; xreg.x = (half_t)0.f; xreg.y = (half_t)0.f;
  if (stage == 0 && tid < 128) {
    float2 v = ((const float2*)(x + (size_t)(chain * TT) * HH))[tid];
    xreg = f2h2(v.x, v.y);
  }

  float* xgq_in  = (stage == 1) ? xg0q : xg1q;
  float* xgq_out = (stage == 0) ? xg0q : xg1q;
  u32* flag_in   = flags + ((size_t)((stage - 1) * BB + chain)) * 32;  // stage>0
  u32* flag_out  = flags + ((size_t)(stage * BB + chain)) * 32;        // stage<3
  u32* cons_in   = cons + ((size_t)((stage - 1) * BB + chain)) * 32;
  u32* cons_out  = cons + ((size_t)(stage * BB + chain)) * 32;

  __syncthreads();

  for (int t = 0; t < TT; ++t) {
    const int slot = t & (DEPTH - 1);
    float xr = 0.f, xz = 0.f, xn = 0.f;

    // ---- protocol waits: single poller ----
    if (tid == 0) {
      if (stage > 0) wait_ge(flag_in + slot, (u32)(t + 1));
      if (stage < 3 && t >= DEPTH) wait_ge(cons_out, (u32)(t - DEPTH + 1));
    }
    __syncthreads();   // B1: block released once data ready

    // ---- payload reads (agent scope = L1 bypass) / LDS fill ----
    if (stage == 0) {
      if (tid < 128) hb[t & 1][tid] = xreg;
    } else if (stage == 2) {
      if (tid < 128) {
        u32 v = ld_u32_agent((const u32*)(h0q + ((size_t)chain * DEPTH + slot) * HH) + tid);
        hb[t & 1][tid] = __builtin_bit_cast(half2_t, v);
      }
    } else {
      if (c == 0) {   // gate inputs; consumed in epilogue (latency hidden by dot)
        const float* q = xgq_in + ((size_t)chain * DEPTH + slot) * G3;
        xr = ld_f32_agent(q + i);
        xz = ld_f32_agent(q + 256 + i);
        xn = ld_f32_agent(q + 512 + i);
      }
    }
    __syncthreads();   // B2: hb fill visible

    // S0: prefetch next x row (plain loads; overlaps the dot)
    if (stage == 0 && tid < 128 && t + 1 < TT) {
      float2 v = ((const float2*)(x + (size_t)(chain * TT + t + 1) * HH))[tid];
      xreg = f2h2(v.x, v.y);
    }

    // ---- GEMV: 3 rows x 128 k per thread, v_dot2_f32_f16 ----
    float a0 = 0.f, a1 = 0.f, a2 = 0.f;
    const float4* hv4 = (const float4*)&hb[t & 1][c * 64];
#pragma unroll
    for (int j4 = 0; j4 < 16; ++j4) {
      float4 q = hv4[j4];
      half2_t hh[4];
      hh[0] = __builtin_bit_cast(half2_t, q.x);
      hh[1] = __builtin_bit_cast(half2_t, q.y);
      hh[2] = __builtin_bit_cast(half2_t, q.z);
      hh[3] = __builtin_bit_cast(half2_t, q.w);
#pragma unroll
      for (int u = 0; u < 4; ++u) {
        const int idx = j4 * 4 + u;
        a0 = __builtin_amdgcn_fdot2(__builtin_bit_cast(half2_t, w[0][idx]), hh[u], a0, false);
        a1 = __builtin_amdgcn_fdot2(__builtin_bit_cast(half2_t, w[1][idx]), hh[u], a1, false);
        a2 = __builtin_amdgcn_fdot2(__builtin_bit_cast(half2_t, w[2][idx]), hh[u], a2, false);
      }
    }
    a0 += __shfl_xor(a0, 1, 64);
    a1 += __shfl_xor(a1, 1, 64);
    a2 += __shfl_xor(a2, 1, 64);

    // ---- epilogue ----
    if (c == 0) {
      if (!rec) {
        float* q = xgq_out + ((size_t)chain * DEPTH + slot) * G3;
        st_f32_agent(q + i,       a0 + bs[0]);
        st_f32_agent(q + 256 + i, a1 + bs[1]);
        st_f32_agent(q + 512 + i, a2 + bs[2]);
      } else {
        float r    = sigm(xr + a0 + bs[0]);
        float z    = sigm(xz + a1 + bs[1]);
        float n    = tanh_fast(xn + r * (a2 + bs[2]));
        float hnew = n + z * (hprev - n);
        hprev = hnew;
        ((half_t*)&hb[(t + 1) & 1][0])[i] = (half_t)hnew;   // state for next step's dot
        if (stage == 1) {
          half_t hv = (half_t)hnew;
          st_u16_agent((u16*)(h0q + ((size_t)chain * DEPTH + slot) * HH + i),
                       __builtin_bit_cast(u16, hv));
        } else {
          out[(size_t)(chain * TT + t) * HH + i] = hnew;    // fp32 output
        }
      }
    }
    __syncthreads();   // B3: all waves' stores drained (vmcnt(0) before s_barrier)

    if (tid == 0) {
      if (stage < 3)
        __hip_atomic_store(flag_out + slot, (u32)(t + 1),
                           __ATOMIC_RELEASE, __HIP_MEMORY_SCOPE_AGENT);
      if (stage > 0)
        __hip_atomic_store(cons_in, (u32)(t + 1),
                           __ATOMIC_RELAXED, __HIP_MEMORY_SCOPE_AGENT);
    }
  }
}

extern "C" void kernel_launch(void* const* d_in, const int* in_sizes, int n_in,
                              void* d_out, int out_size, void* d_ws, size_t ws_size,
                              hipStream_t stream) {
  hipMemsetAsync(d_ws, 0, FLAGS_BYTES, stream);   // zero flags/credits; capture-safe
  hipLaunchKernelGGL(gru_pipe, dim3(128), dim3(512), 0, stream,
                     (const float*)d_in[0], (const float*)d_in[1], (const float*)d_in[2],
                     (const float*)d_in[3], (const float*)d_in[4],
                     (float*)d_out, (uint8_t*)d_ws);
}

// Round 2
// 3276.860 us; speedup vs baseline: 2.3987x; 2.3987x over previous
//
#include <hip/hip_runtime.h>

typedef _Float16 half_t;
typedef _Float16 half2_t __attribute__((ext_vector_type(2)));
typedef unsigned int       u32;
typedef unsigned short     u16;

#define BB    32      // batch
#define TT    2048    // seq len
#define HH    256     // hidden = input dim
#define G3    768     // 3*H
#define DEPTH 8       // ring-buffer slots (2 chunks of 4)
#define CHUNK 4       // timesteps per protocol transaction
#define NCK   (TT / CHUNK)

// ws layout (bytes), ~1.65 MB total (unchanged):
//   0       : flags[3][BB] padded 128B each (u32[parity] in first 8B)
//   12288   : cons [3][BB] padded 128B each
//   24576   : xg0q [BB][DEPTH][G3] f32
//   811008  : xg1q [BB][DEPTH][G3] f32
//   1597440 : h0q  [BB][DEPTH][HH] f16
#define OFF_CONS 12288
#define OFF_XG0  24576
#define OFF_XG1  811008
#define OFF_H0   1597440
#define FLAGS_BYTES 24576

__device__ __forceinline__ half2_t f2h2(float a, float b) {
  half2_t r; r.x = (half_t)a; r.y = (half_t)b; return r;
}
__device__ __forceinline__ float sigm(float v) {
  return __builtin_amdgcn_rcpf(1.f + __builtin_amdgcn_exp2f(v * -1.4426950408889634f));
}
__device__ __forceinline__ float tanh_fast(float v) {
  return 1.f - 2.f * __builtin_amdgcn_rcpf(1.f + __builtin_amdgcn_exp2f(v * 2.8853900817779268f));
}
// Relaxed spin (no per-poll cache-maintenance), single acquire on exit to
// order subsequent payload reads and pin compiler ordering.
__device__ __forceinline__ void wait_ge(u32* p, u32 v) {
  while (__hip_atomic_load(p, __ATOMIC_RELAXED, __HIP_MEMORY_SCOPE_AGENT) < v)
    __builtin_amdgcn_s_sleep(1);
  u32 x = __hip_atomic_load(p, __ATOMIC_ACQUIRE, __HIP_MEMORY_SCOPE_AGENT);
  asm volatile("" :: "v"(x));
}
__device__ __forceinline__ float ld_f32_agent(const float* p) {
  return __hip_atomic_load(p, __ATOMIC_RELAXED, __HIP_MEMORY_SCOPE_AGENT);
}
__device__ __forceinline__ u32 ld_u32_agent(const u32* p) {
  return __hip_atomic_load(p, __ATOMIC_RELAXED, __HIP_MEMORY_SCOPE_AGENT);
}
__device__ __forceinline__ void st_f32_agent(float* p, float v) {
  __hip_atomic_store(p, v, __ATOMIC_RELAXED, __HIP_MEMORY_SCOPE_AGENT);
}
__device__ __forceinline__ void st_u16_agent(u16* p, u16 v) {
  __hip_atomic_store(p, v, __ATOMIC_RELAXED, __HIP_MEMORY_SCOPE_AGENT);
}
// LDS-visibility barrier WITHOUT vmcnt(0) drain: global stores stay in flight.
__device__ __forceinline__ void barrier_lds() {
  asm volatile("s_waitcnt lgkmcnt(0)" ::: "memory");
  __builtin_amdgcn_s_barrier();
  asm volatile("" ::: "memory");
}

__device__ __forceinline__ void dot3(const half2_t* hrow, const u32 (&w)[3][64],
                                     float& a0, float& a1, float& a2) {
  const float4* hv4 = (const float4*)hrow;
#pragma unroll
  for (int j4 = 0; j4 < 16; ++j4) {
    float4 q = hv4[j4];
    half2_t hh[4];
    hh[0] = __builtin_bit_cast(half2_t, q.x);
    hh[1] = __builtin_bit_cast(half2_t, q.y);
    hh[2] = __builtin_bit_cast(half2_t, q.z);
    hh[3] = __builtin_bit_cast(half2_t, q.w);
#pragma unroll
    for (int u = 0; u < 4; ++u) {
      const int idx = j4 * 4 + u;
      a0 = __builtin_amdgcn_fdot2(__builtin_bit_cast(half2_t, w[0][idx]), hh[u], a0, false);
      a1 = __builtin_amdgcn_fdot2(__builtin_bit_cast(half2_t, w[1][idx]), hh[u], a1, false);
      a2 = __builtin_amdgcn_fdot2(__builtin_bit_cast(half2_t, w[2][idx]), hh[u], a2, false);
    }
  }
}

// 128 blocks: blockIdx = stage*32 + chain.
//   stage 0: xg0 = Wih0@x_t + bih0       stage 1: GRU cell layer 0 (Whh0)
//   stage 2: xg1 = Wih1@h0_t + bih1      stage 3: GRU cell layer 1 (Whh1) -> out
// Protocol is CHUNK=4 steps per flag: one poll + one drain + one release per
// 4 timesteps. Inside a chunk recurrent stages use lgkmcnt-only barriers.
__global__ __launch_bounds__(512) __attribute__((amdgpu_waves_per_eu(2, 2)))
void gru_pipe(const float* __restrict__ x,     // fp32 [B][T][H]
              const float* __restrict__ Wih,   // fp32 [2][768][256]
              const float* __restrict__ Whh,   // fp32 [2][768][256]
              const float* __restrict__ bih,   // fp32 [2][768]
              const float* __restrict__ bhh,   // fp32 [2][768]
              float* __restrict__ out,         // fp32 [B][T][H]
              uint8_t* __restrict__ ws)
{
  const int stage = blockIdx.x >> 5;
  const int chain = blockIdx.x & 31;
  const int tid   = threadIdx.x;
  const int i     = tid >> 1;   // 0..255
  const int c     = tid & 1;    // k-half
  const int l     = stage >> 1; // layer
  const bool rec  = (stage & 1);

  u32*    flags = (u32*)ws;
  u32*    cons  = (u32*)(ws + OFF_CONS);
  float*  xg0q  = (float*)(ws + OFF_XG0);
  float*  xg1q  = (float*)(ws + OFF_XG1);
  half_t* h0q   = (half_t*)(ws + OFF_H0);

  const float* Wm = (rec ? Whh : Wih) + (size_t)l * G3 * HH;
  const float* bv = (rec ? bhh : bih) + (size_t)l * G3;

  // ---- weights -> 192 VGPRs (fp32 -> f16 RNE), laundered so the RA keeps
  //      them live instead of rematerializing the loads in the t-loop ----
  u32   w[3][64];
  float bs[3];
#pragma unroll
  for (int r = 0; r < 3; ++r) {
    const int row = r * 256 + i;
    const float4* wp = (const float4*)(Wm + (size_t)row * HH + c * 128);
#pragma unroll
    for (int j = 0; j < 32; ++j) {
      float4 v = wp[j];
      w[r][2 * j]     = __builtin_bit_cast(u32, f2h2(v.x, v.y));
      w[r][2 * j + 1] = __builtin_bit_cast(u32, f2h2(v.z, v.w));
    }
    bs[r] = bv[row];
  }
#pragma unroll
  for (int r = 0; r < 3; ++r)
#pragma unroll
    for (int j = 0; j < 64; ++j)
      asm volatile("" : "+v"(w[r][j]));

  // hb4: !rec stages use 4 step slots; rec stages ping-pong on slots 0/1.
  __shared__ __align__(16) half2_t hb4[CHUNK][128];
  if (tid < 128) {
    half2_t z; z.x = (half_t)0.f; z.y = (half_t)0.f;
#pragma unroll
    for (int s = 0; s < CHUNK; ++s) hb4[s][tid] = z;
  }

  float   hprev = 0.f;
  half2_t xreg[CHUNK];
  if (stage == 0 && tid < 128) {
#pragma unroll
    for (int s = 0; s < CHUNK; ++s) {
      float2 v = ((const float2*)(x + (size_t)(chain * TT + s) * HH))[tid];
      xreg[s] = f2h2(v.x, v.y);
    }
  }

  float* xgq_in  = (stage == 1) ? xg0q : xg1q;
  float* xgq_out = (stage == 0) ? xg0q : xg1q;
  u32* flag_in   = flags + ((size_t)((stage - 1) * BB + chain)) * 32;  // stage>0
  u32* flag_out  = flags + ((size_t)(stage * BB + chain)) * 32;        // stage<3
  u32* cons_in   = cons + ((size_t)((stage - 1) * BB + chain)) * 32;
  u32* cons_out  = cons + ((size_t)(stage * BB + chain)) * 32;

  __syncthreads();

  for (int ck = 0; ck < NCK; ++ck) {
    const int p = ck & 1;                          // slot-group parity
    const size_t qs = (size_t)chain * DEPTH + p * CHUNK;  // base slot

    // ---- protocol waits: one poll per chunk ----
    if (tid == 0) {
      if (stage > 0) wait_ge(flag_in + p, (u32)(ck + 1));
      if (stage < 3 && ck >= 2) wait_ge(cons_out, (u32)(ck - 1));
    }
    __syncthreads();   // B1

    if (!rec) {
      // ---- fill hb4 with 4 input vectors ----
      if (stage == 0) {
        if (tid < 128) {
#pragma unroll
          for (int s = 0; s < CHUNK; ++s) hb4[s][tid] = xreg[s];
        }
      } else {  // stage 2: h0 chunk from queue (agent = coherent path)
        if (tid < 128) {
#pragma unroll
          for (int s = 0; s < CHUNK; ++s) {
            u32 v = ld_u32_agent((const u32*)(h0q + (qs + s) * HH) + tid);
            hb4[s][tid] = __builtin_bit_cast(half2_t, v);
          }
        }
      }
      __syncthreads();   // B2: hb4 visible; stage2's h0q reads complete
      if (stage == 2 && tid == 0)   // early credit: stage1 may overwrite group
        __hip_atomic_store(cons_in, (u32)(ck + 1),
                           __ATOMIC_RELAXED, __HIP_MEMORY_SCOPE_AGENT);
      // prefetch next chunk's x (overlaps the dots)
      if (stage == 0 && tid < 128 && ck + 1 < NCK) {
#pragma unroll
        for (int s = 0; s < CHUNK; ++s) {
          float2 v = ((const float2*)(x + (size_t)(chain * TT + (ck + 1) * CHUNK + s) * HH))[tid];
          xreg[s] = f2h2(v.x, v.y);
        }
      }
      // ---- 4 independent GEMVs, back-to-back ----
#pragma unroll
      for (int s = 0; s < CHUNK; ++s) {
        float a0 = 0.f, a1 = 0.f, a2 = 0.f;
        dot3(&hb4[s][c * 64], w, a0, a1, a2);
        a0 += __shfl_xor(a0, 1, 64);
        a1 += __shfl_xor(a1, 1, 64);
        a2 += __shfl_xor(a2, 1, 64);
        if (c == 0) {
          float* qo = xgq_out + (qs + s) * G3;
          st_f32_agent(qo + i,       a0 + bs[0]);
          st_f32_agent(qo + 256 + i, a1 + bs[1]);
          st_f32_agent(qo + 512 + i, a2 + bs[2]);
        }
      }
      __syncthreads();   // drain: all threads' queue stores acked
      if (tid == 0)
        __hip_atomic_store(flag_out + p, (u32)(ck + 1),
                           __ATOMIC_RELEASE, __HIP_MEMORY_SCOPE_AGENT);
    } else {
      // ---- recurrent cell: gate inputs for all 4 steps up front ----
      float xr[CHUNK] = {0}, xz[CHUNK] = {0}, xn[CHUNK] = {0};
      if (c == 0) {
        const float* q0 = xgq_in + qs * G3;
#pragma unroll
        for (int s = 0; s < CHUNK; ++s) {
          xr[s] = ld_f32_agent(q0 + s * G3 + i);
          xz[s] = ld_f32_agent(q0 + s * G3 + 256 + i);
          xn[s] = ld_f32_agent(q0 + s * G3 + 512 + i);
        }
      }
#pragma unroll
      for (int s = 0; s < CHUNK; ++s) {
        float a0 = 0.f, a1 = 0.f, a2 = 0.f;
        dot3(&hb4[s & 1][c * 64], w, a0, a1, a2);
        a0 += __shfl_xor(a0, 1, 64);
        a1 += __shfl_xor(a1, 1, 64);
        a2 += __shfl_xor(a2, 1, 64);
        if (c == 0) {
          float r    = sigm(xr[s] + a0 + bs[0]);
          float z    = sigm(xz[s] + a1 + bs[1]);
          float n    = tanh_fast(xn[s] + r * (a2 + bs[2]));
          float hnew = n + z * (hprev - n);
          hprev = hnew;
          ((half_t*)&hb4[(s + 1) & 1][0])[i] = (half_t)hnew;   // next step's input
          if (stage == 1) {
            half_t hv = (half_t)hnew;
            st_u16_agent((u16*)(h0q + (qs + s) * HH + i),
                         __builtin_bit_cast(u16, hv));
          } else {
            out[(size_t)(chain * TT + ck * CHUNK + s) * HH + i] = hnew;
          }
        }
        if (s < CHUNK - 1) barrier_lds();   // hb visible; stores stay in flight
      }
      if (stage == 1) {
        __syncthreads();   // drain h0q stores before release
        if (tid == 0) {
          __hip_atomic_store(flag_out + p, (u32)(ck + 1),
                             __ATOMIC_RELEASE, __HIP_MEMORY_SCOPE_AGENT);
          __hip_atomic_store(cons_in, (u32)(ck + 1),
                             __ATOMIC_RELAXED, __HIP_MEMORY_SCOPE_AGENT);
        }
      } else {  // stage 3: reads consumed; no drain needed for out stores
        barrier_lds();
        if (tid == 0)
          __hip_atomic_store(cons_in, (u32)(ck + 1),
                             __ATOMIC_RELAXED, __HIP_MEMORY_SCOPE_AGENT);
      }
    }
  }
}

extern "C" void kernel_launch(void* const* d_in, const int* in_sizes, int n_in,
                              void* d_out, int out_size, void* d_ws, size_t ws_size,
                              hipStream_t stream) {
  hipMemsetAsync(d_ws, 0, FLAGS_BYTES, stream);
  hipLaunchKernelGGL(gru_pipe, dim3(128), dim3(512), 0, stream,
                     (const float*)d_in[0], (const float*)d_in[1], (const float*)d_in[2],
                     (const float*)d_in[3], (const float*)d_in[4],
                     (float*)d_out, (uint8_t*)d_ws);
}